// Round 1
// baseline (64.742 us; speedup 1.0000x reference)
//
#include <hip/hip_runtime.h>
#include <math.h>

// Bilateral filter, 5x5, reflect pad, sigma_spatial=2.0, sigma_range=0.1
// image: (16, 3, 512, 512) fp32 -> out same shape fp32.

#define IMG_H 512
#define IMG_W 512

__device__ __forceinline__ float fexp2(float x) {
#if __has_builtin(__builtin_amdgcn_exp2f)
    return __builtin_amdgcn_exp2f(x);   // v_exp_f32 (computes 2^x)
#else
    return exp2f(x);
#endif
}

__device__ __forceinline__ float frcp(float x) {
#if __has_builtin(__builtin_amdgcn_rcpf)
    return __builtin_amdgcn_rcpf(x);    // v_rcp_f32
#else
    return 1.0f / x;
#endif
}

// Each thread computes 4 contiguous x-pixels of one row of one (b,c) plane.
// tid bits: [6:0] = x-group (128 groups of 4), [15:7] = y (512), [..:16] = plane.
__global__ __launch_bounds__(256) void bilateral5x5_kernel(
        const float* __restrict__ img, float* __restrict__ out) {
    const int tid = blockIdx.x * 256 + threadIdx.x;
    const int xg = tid & 127;
    const int y  = (tid >> 7) & 511;
    const int p  = tid >> 16;

    const float* __restrict__ plane = img + (size_t)p * (IMG_H * IMG_W);
    float* __restrict__ oplane      = out + (size_t)p * (IMG_H * IMG_W);
    const int x0 = xg << 2;

    // log2-domain constants:
    //   range:   exp(-d^2 * 50)            -> d^2 * (-50*log2(e))
    //   spatial: exp(-(dy^2+dx^2) * 0.125) -> -(dy^2+dx^2) * 0.125*log2(e)
    const float RCOEF = -72.13475204444817f;   // -50 * log2(e)
    const float SCOEF = -0.18033688011112042f; // -0.125 * log2(e)

    // center pixels
    const float4 ctr = *reinterpret_cast<const float4*>(plane + (size_t)y * IMG_W + x0);
    const float c[4] = {ctr.x, ctr.y, ctr.z, ctr.w};

    float acc[4] = {0.f, 0.f, 0.f, 0.f};
    float nrm[4] = {0.f, 0.f, 0.f, 0.f};

    // x-border handling (PAD=2): reflected cols fall inside the central float4,
    // so we only need in-bounds clamped loads + per-lane selects (no divergence).
    const bool xlo = (xg == 0);
    const bool xhi = (xg == 127);
    const int lo_x = xlo ? 0 : (x0 - 2);            // 8B-aligned (x0 mult of 4)
    const int hi_x = xhi ? (IMG_W - 2) : (x0 + 4);  // 8B-aligned, in-bounds

#pragma unroll
    for (int dy = -2; dy <= 2; ++dy) {
        int yy = y + dy;
        yy = (yy < 0) ? -yy : yy;                       // reflect top
        yy = (yy >= IMG_H) ? (2 * IMG_H - 2 - yy) : yy; // reflect bottom
        const float* __restrict__ row = plane + (size_t)yy * IMG_W;

        const float2 lo  = *reinterpret_cast<const float2*>(row + lo_x);
        const float4 mid = *reinterpret_cast<const float4*>(row + x0);
        const float2 hi  = *reinterpret_cast<const float2*>(row + hi_x);

        // window cols x0-2 .. x0+5
        float win[8];
        win[0] = xlo ? mid.z : lo.x;   // col -2 -> reflect -> col 2
        win[1] = xlo ? mid.y : lo.y;   // col -1 -> reflect -> col 1
        win[2] = mid.x;
        win[3] = mid.y;
        win[4] = mid.z;
        win[5] = mid.w;
        win[6] = xhi ? mid.z : hi.x;   // col 512 -> reflect -> col 510
        win[7] = xhi ? mid.y : hi.y;   // col 513 -> reflect -> col 509

#pragma unroll
        for (int dx = -2; dx <= 2; ++dx) {
            const float slog2 = (float)(dy * dy + dx * dx) * SCOEF;
#pragma unroll
            for (int px = 0; px < 4; ++px) {
                const float n = win[px + dx + 2];
                const float d = c[px] - n;
                const float t = fmaf(d * d, RCOEF, slog2);
                const float w = fexp2(t);
                acc[px] = fmaf(w, n, acc[px]);
                nrm[px] += w;
            }
        }
    }

    float4 o;
    o.x = acc[0] * frcp(nrm[0] + 1e-8f);
    o.y = acc[1] * frcp(nrm[1] + 1e-8f);
    o.z = acc[2] * frcp(nrm[2] + 1e-8f);
    o.w = acc[3] * frcp(nrm[3] + 1e-8f);
    *reinterpret_cast<float4*>(oplane + (size_t)y * IMG_W + x0) = o;
}

extern "C" void kernel_launch(void* const* d_in, const int* in_sizes, int n_in,
                              void* d_out, int out_size, void* d_ws, size_t ws_size,
                              hipStream_t stream) {
    const float* img = (const float*)d_in[0];
    float* out = (float*)d_out;

    const int n = in_sizes[0];                 // 16*3*512*512 = 12,582,912
    const int threads = n / 4;                 // 4 pixels per thread
    const int block = 256;
    const int grid = threads / block;          // 12288

    bilateral5x5_kernel<<<grid, block, 0, stream>>>(img, out);
}

// Round 2
// 51.229 us; speedup vs baseline: 1.2638x; 1.2638x over previous
//
#include <hip/hip_runtime.h>
#include <math.h>

// Bilateral filter, 5x5, reflect pad, sigma_spatial=2.0, sigma_range=0.1
// image: (16, 3, 512, 512) fp32 -> out same shape fp32.
//
// R2: packed-fp32 (v_pk_*) pixel pairs, image pre-scaled by sqrt(50*log2e)
// so each tap is {pk_sub, pk_fma(-d,d,s), 2x v_exp, pk_fma, pk_add}.

#define IMG_H 512
#define IMG_W 512

typedef float v2f __attribute__((ext_vector_type(2)));

__device__ __forceinline__ float fexp2(float x) {
#if __has_builtin(__builtin_amdgcn_exp2f)
    return __builtin_amdgcn_exp2f(x);   // v_exp_f32 (2^x)
#else
    return exp2f(x);
#endif
}

__device__ __forceinline__ float frcp(float x) {
#if __has_builtin(__builtin_amdgcn_rcpf)
    return __builtin_amdgcn_rcpf(x);    // v_rcp_f32
#else
    return 1.0f / x;
#endif
}

// Each thread computes 8 contiguous x-pixels of one row of one (b,c) plane.
// tid bits: [5:0] = x-group (64 groups of 8) -> y is wave-uniform,
//           [14:6] = y (512), [..:15] = plane (48 planes).
__global__ __launch_bounds__(256) void bilateral5x5_kernel(
        const float* __restrict__ img, float* __restrict__ out) {
    const int tid = blockIdx.x * 256 + threadIdx.x;
    const int xg = tid & 63;
    const int y  = (tid >> 6) & 511;
    const int p  = tid >> 15;

    const float* __restrict__ plane = img + (size_t)p * (IMG_H * IMG_W);
    float* __restrict__ oplane      = out + (size_t)p * (IMG_H * IMG_W);
    const int x0 = xg << 3;

    // S = sqrt(50 * log2(e));  t = slog2 - (S*(c-n))^2  ->  w = 2^t
    const float S = 8.4932180028801907f;
    const float SCOEF = -0.18033688011112042f; // -0.125 * log2(e) (spatial, log2 domain)

    // center pixels, pre-scaled
    const float4 c1 = *reinterpret_cast<const float4*>(plane + (size_t)y * IMG_W + x0);
    const float4 c2 = *reinterpret_cast<const float4*>(plane + (size_t)y * IMG_W + x0 + 4);
    v2f cc[4];
    cc[0] = (v2f){c1.x * S, c1.y * S};
    cc[1] = (v2f){c1.z * S, c1.w * S};
    cc[2] = (v2f){c2.x * S, c2.y * S};
    cc[3] = (v2f){c2.z * S, c2.w * S};

    v2f acc[4] = {{0.f,0.f},{0.f,0.f},{0.f,0.f},{0.f,0.f}};
    v2f nrm[4] = {{0.f,0.f},{0.f,0.f},{0.f,0.f},{0.f,0.f}};

    // x-border (PAD=2): reflected cols land inside the central 8 -> selects only,
    // with clamped in-bounds (8B-aligned) load addresses; zero divergence.
    const bool xlo = (xg == 0);
    const bool xhi = (xg == 63);
    const int lo_x = xlo ? 0 : (x0 - 2);
    const int hi_x = xhi ? (IMG_W - 2) : (x0 + 8);

#pragma unroll
    for (int dy = -2; dy <= 2; ++dy) {
        int yy = y + dy;
        yy = (yy < 0) ? -yy : yy;                       // reflect top
        yy = (yy >= IMG_H) ? (2 * IMG_H - 2 - yy) : yy; // reflect bottom
        const float* __restrict__ row = plane + (size_t)yy * IMG_W;

        const float2 lo = *reinterpret_cast<const float2*>(row + lo_x);
        const float4 m1 = *reinterpret_cast<const float4*>(row + x0);
        const float4 m2 = *reinterpret_cast<const float4*>(row + x0 + 4);
        const float2 hi = *reinterpret_cast<const float2*>(row + hi_x);

        // window cols x0-2 .. x0+9, pre-scaled by S
        float win[12];
        win[0]  = (xlo ? m1.z : lo.x) * S;  // col -2 -> reflect -> col 2
        win[1]  = (xlo ? m1.y : lo.y) * S;  // col -1 -> reflect -> col 1
        win[2]  = m1.x * S;
        win[3]  = m1.y * S;
        win[4]  = m1.z * S;
        win[5]  = m1.w * S;
        win[6]  = m2.x * S;
        win[7]  = m2.y * S;
        win[8]  = m2.z * S;
        win[9]  = m2.w * S;
        win[10] = (xhi ? m2.z : hi.x) * S;  // col 512 -> col 510
        win[11] = (xhi ? m2.y : hi.y) * S;  // col 513 -> col 509

#pragma unroll
        for (int dx = 0; dx < 5; ++dx) {
            const float sl = (float)(dy * dy + (dx - 2) * (dx - 2)) * SCOEF;
            const v2f slv = (v2f){sl, sl};
#pragma unroll
            for (int pr = 0; pr < 4; ++pr) {
                const v2f nn = (v2f){win[2 * pr + dx], win[2 * pr + dx + 1]};
                const v2f d  = cc[pr] - nn;
                const v2f t  = __builtin_elementwise_fma(-d, d, slv);
                v2f w;
                w.x = fexp2(t.x);
                w.y = fexp2(t.y);
                acc[pr] = __builtin_elementwise_fma(w, nn, acc[pr]);
                nrm[pr] = nrm[pr] + w;
            }
        }
    }

    // out = (acc/S) / (nrm + 1e-8) = acc * rcp(S*nrm + S*1e-8)
    const float Seps = S * 1e-8f;
    float4 o1, o2;
    o1.x = acc[0].x * frcp(fmaf(nrm[0].x, S, Seps));
    o1.y = acc[0].y * frcp(fmaf(nrm[0].y, S, Seps));
    o1.z = acc[1].x * frcp(fmaf(nrm[1].x, S, Seps));
    o1.w = acc[1].y * frcp(fmaf(nrm[1].y, S, Seps));
    o2.x = acc[2].x * frcp(fmaf(nrm[2].x, S, Seps));
    o2.y = acc[2].y * frcp(fmaf(nrm[2].y, S, Seps));
    o2.z = acc[3].x * frcp(fmaf(nrm[3].x, S, Seps));
    o2.w = acc[3].y * frcp(fmaf(nrm[3].y, S, Seps));
    *reinterpret_cast<float4*>(oplane + (size_t)y * IMG_W + x0)     = o1;
    *reinterpret_cast<float4*>(oplane + (size_t)y * IMG_W + x0 + 4) = o2;
}

extern "C" void kernel_launch(void* const* d_in, const int* in_sizes, int n_in,
                              void* d_out, int out_size, void* d_ws, size_t ws_size,
                              hipStream_t stream) {
    const float* img = (const float*)d_in[0];
    float* out = (float*)d_out;

    const int n = in_sizes[0];                 // 16*3*512*512 = 12,582,912
    const int threads = n / 8;                 // 8 pixels per thread
    const int block = 256;
    const int grid = threads / block;          // 6144

    bilateral5x5_kernel<<<grid, block, 0, stream>>>(img, out);
}

// Round 3
// 49.840 us; speedup vs baseline: 1.2990x; 1.0279x over previous
//
#include <hip/hip_runtime.h>
#include <math.h>

// Bilateral filter, 5x5, reflect pad, sigma_spatial=2.0, sigma_range=0.1
// image: (16, 3, 512, 512) fp32 -> out same shape fp32.
//
// R3: forced packed-fp32 math (v_pk_add_f32 / v_pk_fma_f32 inline asm,
// double-rate on gfx950). Pixel pairing (px, px+4) so all MFMA... er, all
// pk operands are pre-built aligned pairs P[i] = {w[i-2], w[i+2]} * S,
// constructed once per row by the scaling muls. Center tap (w==1) free.
// w = exp2(sl - d^2) computed as v_exp_f32(-(d^2 + q)), q = -sl >= 0,
// with the negation folded into the exp's VOP3 src modifier.

#define IMG_H 512
#define IMG_W 512

typedef float v2f __attribute__((ext_vector_type(2)));

__device__ __forceinline__ float frcp(float x) {
    return __builtin_amdgcn_rcpf(x);    // v_rcp_f32
}

__device__ __forceinline__ v2f pk_add(v2f a, v2f b) {
    v2f r;
    asm("v_pk_add_f32 %0, %1, %2" : "=v"(r) : "v"(a), "v"(b));
    return r;
}
__device__ __forceinline__ v2f pk_fma(v2f a, v2f b, v2f c) {
    v2f r;
    asm("v_pk_fma_f32 %0, %1, %2, %3" : "=v"(r) : "v"(a), "v"(b), "v"(c));
    return r;
}
// 2^(-x), negation via VOP3 source modifier (free)
__device__ __forceinline__ float exp2neg(float x) {
    float r;
    asm("v_exp_f32 %0, -%1" : "=v"(r) : "v"(x));
    return r;
}

// Each thread computes 8 contiguous x-pixels of one row of one (b,c) plane.
// tid bits: [5:0] = x-group (64 groups of 8) -> y,p wave-uniform (SGPR math),
//           [14:6] = y (512), [..:15] = plane (48 planes).
__global__ __launch_bounds__(256) void bilateral5x5_kernel(
        const float* __restrict__ img, float* __restrict__ out) {
    const int tid = blockIdx.x * 256 + threadIdx.x;
    const int xg = tid & 63;
    const int y  = (tid >> 6) & 511;
    const int p  = tid >> 15;

    const float* __restrict__ plane = img + (size_t)p * (IMG_H * IMG_W);
    float* __restrict__ oplane      = out + (size_t)p * (IMG_H * IMG_W);
    const int x0 = xg << 3;

    // S = sqrt(50 * log2(e)); d = S*(n - c); w = exp2(-(d^2 + q)),
    // q = (dy^2+dx^2) * 0.125*log2(e)  (positive)
    const float S = 8.4932180028801907f;
    const float QC = 0.18033688011112042f;

    // x-border (PAD=2): reflected cols land inside the central 8 ->
    // clamped in-bounds load addresses + 4 selects per row, no divergence.
    const bool xlo = (xg == 0);
    const bool xhi = (xg == 63);
    const int off_m0 = xlo ? x0 : (x0 - 4);
    const int off_m3 = xhi ? (x0 + 4) : (x0 + 8);

    // center pixels, scaled by -S (pre-negated so d = pk_add(nn, ncc))
    const float4 c1 = *reinterpret_cast<const float4*>(plane + (size_t)y * IMG_W + x0);
    const float4 c2 = *reinterpret_cast<const float4*>(plane + (size_t)y * IMG_W + x0 + 4);
    v2f ncc[4];
    ncc[0] = (v2f){c1.x * -S, c2.x * -S};
    ncc[1] = (v2f){c1.y * -S, c2.y * -S};
    ncc[2] = (v2f){c1.z * -S, c2.z * -S};
    ncc[3] = (v2f){c1.w * -S, c2.w * -S};

    v2f acc[4] = {{0.f,0.f},{0.f,0.f},{0.f,0.f},{0.f,0.f}};
    v2f nrm[4] = {{0.f,0.f},{0.f,0.f},{0.f,0.f},{0.f,0.f}};
    const v2f one2 = {1.0f, 1.0f};

#pragma unroll
    for (int dy = -2; dy <= 2; ++dy) {
        int yy = y + dy;
        yy = (yy < 0) ? -yy : yy;                 // reflect top
        yy = (yy > 511) ? (1022 - yy) : yy;       // reflect bottom
        const float* __restrict__ row = plane + (size_t)yy * IMG_W;

        const float4 m0 = *reinterpret_cast<const float4*>(row + off_m0);
        const float4 m1 = *reinterpret_cast<const float4*>(row + x0);
        const float4 m2 = *reinterpret_cast<const float4*>(row + x0 + 4);
        const float4 m3 = *reinterpret_cast<const float4*>(row + off_m3);

        // window w[x0-2 .. x0+9]; pairs P[i] = {w[i-2], w[i+2]} * S
        const float w_m2 = xlo ? m1.z : m0.z;   // col -2 -> reflect col 2
        const float w_m1 = xlo ? m1.y : m0.w;   // col -1 -> reflect col 1
        const float w_8  = xhi ? m2.z : m3.x;   // col 512 -> reflect col 510
        const float w_9  = xhi ? m2.y : m3.y;   // col 513 -> reflect col 509

        v2f P[8];
        P[0] = (v2f){w_m2 * S, m1.z * S};
        P[1] = (v2f){w_m1 * S, m1.w * S};
        P[2] = (v2f){m1.x * S, m2.x * S};
        P[3] = (v2f){m1.y * S, m2.y * S};
        P[4] = (v2f){m1.z * S, m2.z * S};
        P[5] = (v2f){m1.w * S, m2.w * S};
        P[6] = (v2f){m2.x * S, w_8 * S};
        P[7] = (v2f){m2.y * S, w_9 * S};

#pragma unroll
        for (int dx = -2; dx <= 2; ++dx) {
            const float q = (float)(dy * dy + dx * dx) * QC;
            const v2f qv = {q, q};
#pragma unroll
            for (int pr = 0; pr < 4; ++pr) {
                const v2f nn = P[pr + dx + 2];
                if (dy == 0 && dx == 0) {
                    // center: w = exp2(0) = 1 exactly
                    acc[pr] = pk_add(acc[pr], nn);
                    nrm[pr] = pk_add(nrm[pr], one2);
                } else {
                    const v2f d = pk_add(nn, ncc[pr]);   // S*(n - c)
                    const v2f t = pk_fma(d, d, qv);      // d^2 + q
                    v2f w;
                    w.x = exp2neg(t.x);                  // 2^(-(d^2+q))
                    w.y = exp2neg(t.y);
                    acc[pr] = pk_fma(w, nn, acc[pr]);
                    nrm[pr] = pk_add(nrm[pr], w);
                }
            }
        }
    }

    // out = (acc/S) / (nrm + 1e-8) = acc * rcp(S*nrm + S*1e-8)
    const float Seps = S * 1e-8f;
    float4 o1, o2;
    o1.x = acc[0].x * frcp(fmaf(nrm[0].x, S, Seps));
    o1.y = acc[1].x * frcp(fmaf(nrm[1].x, S, Seps));
    o1.z = acc[2].x * frcp(fmaf(nrm[2].x, S, Seps));
    o1.w = acc[3].x * frcp(fmaf(nrm[3].x, S, Seps));
    o2.x = acc[0].y * frcp(fmaf(nrm[0].y, S, Seps));
    o2.y = acc[1].y * frcp(fmaf(nrm[1].y, S, Seps));
    o2.z = acc[2].y * frcp(fmaf(nrm[2].y, S, Seps));
    o2.w = acc[3].y * frcp(fmaf(nrm[3].y, S, Seps));
    *reinterpret_cast<float4*>(oplane + (size_t)y * IMG_W + x0)     = o1;
    *reinterpret_cast<float4*>(oplane + (size_t)y * IMG_W + x0 + 4) = o2;
}

extern "C" void kernel_launch(void* const* d_in, const int* in_sizes, int n_in,
                              void* d_out, int out_size, void* d_ws, size_t ws_size,
                              hipStream_t stream) {
    const float* img = (const float*)d_in[0];
    float* out = (float*)d_out;

    const int n = in_sizes[0];                 // 16*3*512*512 = 12,582,912
    const int threads = n / 8;                 // 8 pixels per thread
    const int block = 256;
    const int grid = threads / block;          // 6144

    bilateral5x5_kernel<<<grid, block, 0, stream>>>(img, out);
}

// Round 4
// 49.010 us; speedup vs baseline: 1.3210x; 1.0169x over previous
//
#include <hip/hip_runtime.h>
#include <math.h>

// Bilateral filter, 5x5, reflect pad, sigma_spatial=2.0, sigma_range=0.1
// image: (16, 3, 512, 512) fp32 -> out same shape fp32.
//
// R4: fused single-asm-block tap. Each tap-pair is exactly 7 instructions
// (2x v_pk_add, 2x v_pk_fma, 2x v_exp_f32, 1x s_nop) with hard temps v0-v3,
// eliminating all compiler-inserted pair-shuffle movs around the pk/exp ops.
// q constants live in SGPR pairs (SALU, off the VALU pipe).
// Pixel pairing (px, px+4); pairs built for free by the *S window muls.

#define IMG_H 512
#define IMG_W 512

typedef float v2f __attribute__((ext_vector_type(2)));

__device__ __forceinline__ float frcp(float x) {
    return __builtin_amdgcn_rcpf(x);    // v_rcp_f32
}

// acc += w*nn; nrm += w; w = exp2(-((nn+ncc)^2 + q))   [ncc = -S*c, nn = S*n]
__device__ __forceinline__ void tap(v2f& acc, v2f& nrm, v2f nn, v2f ncc, v2f q) {
    asm("v_pk_add_f32 v[0:1], %2, %3\n\t"             // d = nn + ncc
        "v_pk_fma_f32 v[0:1], v[0:1], v[0:1], %4\n\t" // t = d*d + q
        "v_exp_f32 v2, -v0\n\t"                       // w.lo = 2^(-t.lo)
        "v_exp_f32 v3, -v1\n\t"                       // w.hi = 2^(-t.hi)
        "s_nop 0\n\t"                                 // TRANS->VALU wait state
        "v_pk_fma_f32 %0, v[2:3], %2, %0\n\t"         // acc += w * nn
        "v_pk_add_f32 %1, %1, v[2:3]"                 // nrm += w
        : "+v"(acc), "+v"(nrm)
        : "v"(nn), "v"(ncc), "s"(q)
        : "v0", "v1", "v2", "v3");
}

// Each thread computes 8 contiguous x-pixels of one row of one (b,c) plane.
// tid bits: [5:0] = x-group (64 groups of 8) -> y,p wave-uniform,
//           [14:6] = y (512), [..:15] = plane (48 planes).
__global__ __launch_bounds__(256) void bilateral5x5_kernel(
        const float* __restrict__ img, float* __restrict__ out) {
    const int tid = blockIdx.x * 256 + threadIdx.x;
    const int xg = tid & 63;
    const int y  = (tid >> 6) & 511;
    const int p  = tid >> 15;

    const float* __restrict__ plane = img + (size_t)p * (IMG_H * IMG_W);
    float* __restrict__ oplane      = out + (size_t)p * (IMG_H * IMG_W);
    const int x0 = xg << 3;

    // S = sqrt(50 * log2(e)); d = S*(n - c); w = exp2(-(d^2 + q)),
    // q = (dy^2+dx^2) * 0.125*log2(e)
    const float S = 8.4932180028801907f;
    const float QC = 0.18033688011112042f;

    // x-border (PAD=2): reflected cols land inside the central 8 ->
    // clamped in-bounds load addresses + 4 selects per row, no divergence.
    const bool xlo = (xg == 0);
    const bool xhi = (xg == 63);
    const int off_m0 = xlo ? x0 : (x0 - 4);
    const int off_m3 = xhi ? (x0 + 4) : (x0 + 8);

    // center pixels, scaled by -S (pre-negated so d = pk_add(nn, ncc))
    const float4 c1 = *reinterpret_cast<const float4*>(plane + (size_t)y * IMG_W + x0);
    const float4 c2 = *reinterpret_cast<const float4*>(plane + (size_t)y * IMG_W + x0 + 4);
    v2f ncc[4];
    ncc[0] = (v2f){c1.x * -S, c2.x * -S};
    ncc[1] = (v2f){c1.y * -S, c2.y * -S};
    ncc[2] = (v2f){c1.z * -S, c2.z * -S};
    ncc[3] = (v2f){c1.w * -S, c2.w * -S};

    v2f acc[4] = {{0.f,0.f},{0.f,0.f},{0.f,0.f},{0.f,0.f}};
    v2f nrm[4] = {{0.f,0.f},{0.f,0.f},{0.f,0.f},{0.f,0.f}};

#pragma unroll
    for (int dy = -2; dy <= 2; ++dy) {
        int yy = y + dy;
        yy = (yy < 0) ? -yy : yy;                 // reflect top
        yy = (yy > 511) ? (1022 - yy) : yy;       // reflect bottom
        const float* __restrict__ row = plane + (size_t)yy * IMG_W;

        const float4 m0 = *reinterpret_cast<const float4*>(row + off_m0);
        const float4 m1 = *reinterpret_cast<const float4*>(row + x0);
        const float4 m2 = *reinterpret_cast<const float4*>(row + x0 + 4);
        const float4 m3 = *reinterpret_cast<const float4*>(row + off_m3);

        // window w[x0-2 .. x0+9]; pairs P[i] = {w[i-2], w[i+2]} * S
        const float w_m2 = xlo ? m1.z : m0.z;   // col -2 -> reflect col 2
        const float w_m1 = xlo ? m1.y : m0.w;   // col -1 -> reflect col 1
        const float w_8  = xhi ? m2.z : m3.x;   // col 512 -> reflect col 510
        const float w_9  = xhi ? m2.y : m3.y;   // col 513 -> reflect col 509

        v2f P[8];
        P[0] = (v2f){w_m2 * S, m1.z * S};
        P[1] = (v2f){w_m1 * S, m1.w * S};
        P[2] = (v2f){m1.x * S, m2.x * S};
        P[3] = (v2f){m1.y * S, m2.y * S};
        P[4] = (v2f){m1.z * S, m2.z * S};
        P[5] = (v2f){m1.w * S, m2.w * S};
        P[6] = (v2f){m2.x * S, w_8 * S};
        P[7] = (v2f){m2.y * S, w_9 * S};

#pragma unroll
        for (int dx = -2; dx <= 2; ++dx) {
            const float q = (float)(dy * dy + dx * dx) * QC;
            const v2f qv = {q, q};
#pragma unroll
            for (int pr = 0; pr < 4; ++pr) {
                const v2f nn = P[pr + dx + 2];
                if (dy == 0 && dx == 0) {
                    // center: w = exp2(0) = 1 exactly
                    acc[pr] += nn;
                    nrm[pr] += (v2f){1.0f, 1.0f};
                } else {
                    tap(acc[pr], nrm[pr], nn, ncc[pr], qv);
                }
            }
        }
    }

    // out = (acc/S) / (nrm + 1e-8) = acc * rcp(S*nrm + S*1e-8)
    const float Seps = S * 1e-8f;
    float4 o1, o2;
    o1.x = acc[0].x * frcp(fmaf(nrm[0].x, S, Seps));
    o1.y = acc[1].x * frcp(fmaf(nrm[1].x, S, Seps));
    o1.z = acc[2].x * frcp(fmaf(nrm[2].x, S, Seps));
    o1.w = acc[3].x * frcp(fmaf(nrm[3].x, S, Seps));
    o2.x = acc[0].y * frcp(fmaf(nrm[0].y, S, Seps));
    o2.y = acc[1].y * frcp(fmaf(nrm[1].y, S, Seps));
    o2.z = acc[2].y * frcp(fmaf(nrm[2].y, S, Seps));
    o2.w = acc[3].y * frcp(fmaf(nrm[3].y, S, Seps));
    *reinterpret_cast<float4*>(oplane + (size_t)y * IMG_W + x0)     = o1;
    *reinterpret_cast<float4*>(oplane + (size_t)y * IMG_W + x0 + 4) = o2;
}

extern "C" void kernel_launch(void* const* d_in, const int* in_sizes, int n_in,
                              void* d_out, int out_size, void* d_ws, size_t ws_size,
                              hipStream_t stream) {
    const float* img = (const float*)d_in[0];
    float* out = (float*)d_out;

    const int n = in_sizes[0];                 // 16*3*512*512 = 12,582,912
    const int threads = n / 8;                 // 8 pixels per thread
    const int block = 256;
    const int grid = threads / block;          // 6144

    bilateral5x5_kernel<<<grid, block, 0, stream>>>(img, out);
}